// Round 9
// baseline (146.310 us; speedup 1.0000x reference)
//
#include <hip/hip_runtime.h>

#define BB    8
#define NBL   2000
#define RR    10000
#define XDIM  2000
#define GRID  2000
#define TAILB 100          // last 100 blocks: select + GEMV
#define SELB  40
#define TSTART (GRID - TAILB)

// tiny node: re-arm barrier counters every call (ws is poisoned once, not re-zeroed)
__global__ void k_init(unsigned* __restrict__ counters) {
    if (threadIdx.x < 2) counters[threadIdx.x] = 0u;
}

__device__ __forceinline__ unsigned sortkey(float f) {
    unsigned u = __float_as_uint(f);
    return (u & 0x80000000u) ? ~u : (u | 0x80000000u);
}
__device__ __forceinline__ float unsortkey(unsigned u) {
    unsigned ub = (u & 0x80000000u) ? (u ^ 0x80000000u) : ~u;
    return __uint_as_float(ub);
}

// ---------------- fused kernel: GEMM (all 2000 blocks) -> [last 100] select -> GEMV
__global__ __launch_bounds__(256) void k_fused(
    const float* __restrict__ in1, const float* __restrict__ in2,
    const float* __restrict__ in3, const float* __restrict__ in4,
    const float* __restrict__ in5,
    const float* __restrict__ Wfc,  const float* __restrict__ bfc,
    const float* __restrict__ bfv,
    const float* __restrict__ Wmlp, const float* __restrict__ bmlp,
    float* __restrict__ mem2, float* __restrict__ spike_out,
    float* __restrict__ out, unsigned* __restrict__ counters)
{
    const int tid  = threadIdx.x;
    const int wave = tid >> 6, lane = tid & 63;     // wave = column quarter 0..3
    const int nb    = blockIdx.x;                   // 0..1999
    const int rbase = nb * 5;

    // ============ phase 1: GEMM, split-K×4 over the block's 4 waves ============
    {
        float acc[5][BB];
        #pragma unroll
        for (int q = 0; q < 5; ++q)
            #pragma unroll
            for (int b = 0; b < BB; ++b) acc[q][b] = 0.f;

        #pragma unroll
        for (int i = 0; i < 2; ++i) {
            const int col = wave * 512 + i * 256 + (lane << 2);   // float4-aligned
            const bool valid = col < XDIM;          // tail: wave==3,i==1, lanes>=52
            const int wh  = col / 400;              // concat segment
            const int off = col - wh * 400;         // f4 never crosses a 400-boundary
            const float* xp = in1;
            xp = (wh == 1) ? in2 : xp;
            xp = (wh == 2) ? in3 : xp;
            xp = (wh == 3) ? in4 : xp;
            xp = (wh == 4) ? in5 : xp;

            float4 w[5];
            #pragma unroll
            for (int q = 0; q < 5; ++q)
                w[q] = valid ? *(const float4*)(Wfc + (size_t)(rbase + q) * XDIM + col)
                             : make_float4(0.f, 0.f, 0.f, 0.f);

            #pragma unroll
            for (int b = 0; b < BB; ++b) {
                float4 xv = valid ? *(const float4*)(xp + b * 400 + off)
                                  : make_float4(0.f, 0.f, 0.f, 0.f);
                #pragma unroll
                for (int q = 0; q < 5; ++q)
                    acc[q][b] += w[q].x * xv.x + w[q].y * xv.y + w[q].z * xv.z + w[q].w * xv.w;
            }
        }

        __shared__ float part[4][5][BB];            // [wave][q][b], 640 B
        #pragma unroll
        for (int q = 0; q < 5; ++q) {
            #pragma unroll
            for (int b = 0; b < BB; ++b) {
                float v = acc[q][b];
                #pragma unroll
                for (int o = 32; o >= 1; o >>= 1) v += __shfl_xor(v, o, 64);
                if (lane == 0) part[wave][q][b] = v;
            }
        }
        __syncthreads();

        if (wave == 0) {
            if (lane < 40) {                        // q = lane>>3, b = lane&7
                const int q = lane >> 3, b = lane & 7;
                const int r = rbase + q;
                const float v = part[0][q][b] + part[1][q][b] + part[2][q][b] + part[3][q][b];
                mem2[(q * BB + b) * NBL + nb] = v + bfc[r] + bfv[r] + 0.05f;
            }
            __threadfence();                        // release mem2 stores (wave-wide)
            if (lane == 0) atomicAdd(&counters[0], 1u);
        }
    }

    if (blockIdx.x < TSTART) return;                // blocks 0..1899 retire
    const int sel = blockIdx.x - TSTART;            // 0..99 == output column o

    // ============ prefetch W_mlp column into registers (overlaps barrier wait) ====
    // Select blocks (sel<40) defer: they need VGPRs for f[32]/u[32] first.
    float4 wv[10];
    const bool pre = (sel >= SELB);
    if (pre) {
        #pragma unroll
        for (int i = 0; i < 10; ++i) {
            const int col = i * 1024 + tid * 4;
            wv[i] = (col < RR) ? *(const float4*)(Wmlp + (size_t)sel * RR + col)
                               : make_float4(0.f, 0.f, 0.f, 0.f);
        }
    }

    // ---- barrier 1: all 2000 GEMM arrivals
    if (tid == 0) {
        while (__hip_atomic_load(&counters[0], __ATOMIC_ACQUIRE,
                                 __HIP_MEMORY_SCOPE_AGENT) < (unsigned)GRID)
            __builtin_amdgcn_s_sleep(2);
        __threadfence();                            // acquire: invalidate stale lines
    }
    __syncthreads();

    // ============ phase 2: exact order stats + spike (blocks sel<40, wave 0) =====
    if (sel < SELB && tid < 64) {
        const int b = sel / 5, k = sel - b * 5;
        const float* src = mem2 + (k * BB + b) * NBL;

        float    f[32];
        unsigned u[32];
        #pragma unroll
        for (int i = 0; i < 32; ++i) {
            int n = i * 64 + lane;
            f[i] = (n < NBL) ? src[n] : 0.f;
            u[i] = (n < NBL) ? sortkey(f[i]) : 0u;  // pad key = smallest
        }

        // rank-159 (160th largest): max X with count(u >= X) >= 160 (ballot+popc)
        unsigned X = 0;
        for (int bit = 31; bit >= 0; --bit) {
            unsigned cand = X | (1u << bit);
            int c = 0;
            #pragma unroll
            for (int i = 0; i < 32; ++i)
                c += (int)__popcll(__ballot(u[i] >= cand));
            if (c >= 160) X = cand;
        }
        const unsigned q2u = X;                     // mem_q2 (rank 159)

        int cge = 0;
        #pragma unroll
        for (int i = 0; i < 32; ++i)
            cge += (int)__popcll(__ballot(u[i] >= q2u));

        unsigned q1u;
        if (cge >= 161) {
            q1u = q2u;                              // ties reach rank 160
        } else {
            unsigned m = 0;
            #pragma unroll
            for (int i = 0; i < 32; ++i)
                if (u[i] < q2u && u[i] > m) m = u[i];
            #pragma unroll
            for (int o = 32; o >= 1; o >>= 1) {
                unsigned ot = __shfl_xor(m, o, 64);
                m = (ot > m) ? ot : m;
            }
            q1u = m;                                // mem_q1 (rank 160)
        }

        const float q2 = unsortkey(q2u), q1 = unsortkey(q1u);
        const float nps = q1 + (q2 - q1) * 0.2f;

        #pragma unroll
        for (int i = 0; i < 32; ++i) {
            int n = i * 64 + lane;
            if (n < NBL)
                spike_out[b * RR + n * 5 + k] = (f[i] - nps > 0.1f) ? 1.0f : 0.0f;
        }
        __threadfence();                            // release spike stores
        if (lane == 0) atomicAdd(&counters[1], 1u);
    }

    // ---- barrier 2: all 40 select arrivals
    __syncthreads();
    if (tid == 0) {
        while (__hip_atomic_load(&counters[1], __ATOMIC_ACQUIRE,
                                 __HIP_MEMORY_SCOPE_AGENT) < (unsigned)SELB)
            __builtin_amdgcn_s_sleep(2);
        __threadfence();
    }
    __syncthreads();

    // ============ phase 3: GEMV  out[b][sel] = spike[b]·W_mlp[sel] + b_mlp[sel] ===
    if (!pre) {                                     // select blocks load W now
        #pragma unroll
        for (int i = 0; i < 10; ++i) {
            const int col = i * 1024 + tid * 4;
            wv[i] = (col < RR) ? *(const float4*)(Wmlp + (size_t)sel * RR + col)
                               : make_float4(0.f, 0.f, 0.f, 0.f);
        }
    }

    float acc[BB];
    #pragma unroll
    for (int b = 0; b < BB; ++b) acc[b] = 0.f;

    #pragma unroll
    for (int i = 0; i < 10; ++i) {
        const int col = i * 1024 + tid * 4;
        if (col < RR) {
            #pragma unroll
            for (int b = 0; b < BB; ++b) {
                float4 s = *(const float4*)(spike_out + b * RR + col);
                acc[b] += wv[i].x * s.x + wv[i].y * s.y + wv[i].z * s.z + wv[i].w * s.w;
            }
        }
    }

    __shared__ float red[4][BB];
    #pragma unroll
    for (int b = 0; b < BB; ++b) {
        float v = acc[b];
        #pragma unroll
        for (int off = 32; off >= 1; off >>= 1) v += __shfl_xor(v, off, 64);
        if (lane == 0) red[wave][b] = v;
    }
    __syncthreads();
    if (tid < BB) {
        float v = red[0][tid] + red[1][tid] + red[2][tid] + red[3][tid];
        out[tid * 100 + sel] = v + bmlp[sel];
    }
}

extern "C" void kernel_launch(void* const* d_in, const int* in_sizes, int n_in,
                              void* d_out, int out_size, void* d_ws, size_t ws_size,
                              hipStream_t stream) {
    const float* in1  = (const float*)d_in[0];
    const float* in2  = (const float*)d_in[1];
    const float* in3  = (const float*)d_in[2];
    const float* in4  = (const float*)d_in[3];
    const float* in5  = (const float*)d_in[4];
    const float* Wfc  = (const float*)d_in[5];
    const float* bfc  = (const float*)d_in[6];
    // d_in[7] = W_fv : multiplied by zero spikes — never read (saves 400 MB)
    const float* bfv  = (const float*)d_in[8];
    const float* Wmlp = (const float*)d_in[9];
    const float* bmlp = (const float*)d_in[10];

    float* out   = (float*)d_out;          // 8*100 = 800 floats
    float* spike = out + 800;              // 8*10000 floats (r_sumspike)

    float*    mem2     = (float*)d_ws;     // 80000 floats, layout [q][b][nb]
    unsigned* counters = (unsigned*)((char*)d_ws + 80000 * sizeof(float));

    k_init<<<1, 64, 0, stream>>>(counters);
    k_fused<<<GRID, 256, 0, stream>>>(in1, in2, in3, in4, in5, Wfc, bfc, bfv,
                                      Wmlp, bmlp, mem2, spike, out, counters);
}

// Round 10
// 99.142 us; speedup vs baseline: 1.4758x; 1.4758x over previous
//
#include <hip/hip_runtime.h>

#define BB   8
#define NBL  2000
#define RR   10000
#define XDIM 2000

// ---------------- kernel A (split-K×4): mem2[q][b][nb] = x[b]·W_fc[nb*5+q] + biases
// 2000 blocks × 256 thr. Block owns ONE nb; its 4 waves cover 512-col quarters.
// DIAGNOSTIC THIS ROUND: launched TWICE (idempotent) to measure kA's marginal cost.
__global__ __launch_bounds__(256) void kA_gemm(
    const float* __restrict__ in1, const float* __restrict__ in2,
    const float* __restrict__ in3, const float* __restrict__ in4,
    const float* __restrict__ in5,
    const float* __restrict__ Wfc, const float* __restrict__ bfc,
    const float* __restrict__ bfv, float* __restrict__ mem2,
    unsigned* __restrict__ counter)
{
    // re-arm the kernel-B barrier every call (stream order publishes it before kB)
    if (blockIdx.x == 0 && threadIdx.x == 0) *counter = 0u;

    const int tid  = threadIdx.x;
    const int wave = tid >> 6, lane = tid & 63;     // wave = column quarter 0..3
    const int nb    = blockIdx.x;                   // 0..1999
    const int rbase = nb * 5;

    float acc[5][BB];
    #pragma unroll
    for (int q = 0; q < 5; ++q)
        #pragma unroll
        for (int b = 0; b < BB; ++b) acc[q][b] = 0.f;

    #pragma unroll
    for (int i = 0; i < 2; ++i) {
        const int col = wave * 512 + i * 256 + (lane << 2);   // float4-aligned
        const bool valid = col < XDIM;              // tail: wave==3,i==1, lanes>=52
        const int wh  = col / 400;                  // concat segment (5 only if invalid)
        const int off = col - wh * 400;             // f4 never crosses a 400-boundary
        const float* xp = in1;
        xp = (wh == 1) ? in2 : xp;
        xp = (wh == 2) ? in3 : xp;
        xp = (wh == 3) ? in4 : xp;
        xp = (wh == 4) ? in5 : xp;

        float4 w[5];
        #pragma unroll
        for (int q = 0; q < 5; ++q)
            w[q] = valid ? *(const float4*)(Wfc + (size_t)(rbase + q) * XDIM + col)
                         : make_float4(0.f, 0.f, 0.f, 0.f);

        #pragma unroll
        for (int b = 0; b < BB; ++b) {
            float4 xv = valid ? *(const float4*)(xp + b * 400 + off)
                              : make_float4(0.f, 0.f, 0.f, 0.f);
            #pragma unroll
            for (int q = 0; q < 5; ++q)
                acc[q][b] += w[q].x * xv.x + w[q].y * xv.y + w[q].z * xv.z + w[q].w * xv.w;
        }
    }

    // intra-wave reduce -> LDS partials -> wave 0 finalizes
    __shared__ float part[4][5][BB];                // [wave][q][b], 640 B
    #pragma unroll
    for (int q = 0; q < 5; ++q) {
        #pragma unroll
        for (int b = 0; b < BB; ++b) {
            float v = acc[q][b];
            #pragma unroll
            for (int o = 32; o >= 1; o >>= 1) v += __shfl_xor(v, o, 64);
            if (lane == 0) part[wave][q][b] = v;
        }
    }
    __syncthreads();

    if (wave == 0 && lane < 40) {                   // 40 outputs: q = lane>>3, b = lane&7
        const int q = lane >> 3, b = lane & 7;
        const int r = rbase + q;
        const float v = part[0][q][b] + part[1][q][b] + part[2][q][b] + part[3][q][b];
        mem2[(q * BB + b) * NBL + nb] = v + bfc[r] + bfv[r] + 0.05f;
    }
}

// ---------------- kernel B: fused {radix-select nps + spike} -> barrier -> MLP GEMV
__device__ __forceinline__ unsigned sortkey(float f) {
    unsigned u = __float_as_uint(f);
    return (u & 0x80000000u) ? ~u : (u | 0x80000000u);
}
__device__ __forceinline__ float unsortkey(unsigned u) {
    unsigned ub = (u & 0x80000000u) ? (u ^ 0x80000000u) : ~u;
    return __uint_as_float(ub);
}

__global__ __launch_bounds__(512) void kB_spike_out(
    const float* __restrict__ mem2, const float* __restrict__ Wmlp,
    const float* __restrict__ bmlp, float* __restrict__ spike_out,
    float* __restrict__ out, unsigned* __restrict__ counter)
{
    const int tid = threadIdx.x;
    const int blk = blockIdx.x;                      // 100 blocks

    // ---- phase A: blocks 0..39, wave 0 only — exact order stats + spike write
    if (blk < 40 && tid < 64) {
        const int b = blk / 5, k = blk - b * 5;
        const int lane = tid;
        const float* src = mem2 + (k * BB + b) * NBL;

        float    f[32];
        unsigned u[32];
        #pragma unroll
        for (int i = 0; i < 32; ++i) {
            int nb = i * 64 + lane;
            f[i] = (nb < NBL) ? src[nb] : 0.f;
            u[i] = (nb < NBL) ? sortkey(f[i]) : 0u;  // pad key = smallest
        }

        // rank-159 (160th largest): max X with count(u >= X) >= 160 (ballot+popc)
        unsigned X = 0;
        for (int bit = 31; bit >= 0; --bit) {
            unsigned cand = X | (1u << bit);
            int c = 0;
            #pragma unroll
            for (int i = 0; i < 32; ++i)
                c += (int)__popcll(__ballot(u[i] >= cand));
            if (c >= 160) X = cand;
        }
        const unsigned q2u = X;                      // mem_q2 (rank 159)

        int cge = 0;
        #pragma unroll
        for (int i = 0; i < 32; ++i)
            cge += (int)__popcll(__ballot(u[i] >= q2u));

        unsigned q1u;
        if (cge >= 161) {
            q1u = q2u;                               // ties reach rank 160
        } else {
            unsigned m = 0;
            #pragma unroll
            for (int i = 0; i < 32; ++i)
                if (u[i] < q2u && u[i] > m) m = u[i];
            #pragma unroll
            for (int o = 32; o >= 1; o >>= 1) {
                unsigned ot = __shfl_xor(m, o, 64);
                m = (ot > m) ? ot : m;
            }
            q1u = m;                                 // mem_q1 (rank 160)
        }

        const float q2 = unsortkey(q2u), q1 = unsortkey(q1u);
        const float nps = q1 + (q2 - q1) * 0.2f;

        #pragma unroll
        for (int i = 0; i < 32; ++i) {
            int nb = i * 64 + lane;
            if (nb < NBL)
                spike_out[b * RR + nb * 5 + k] = (f[i] - nps > 0.1f) ? 1.0f : 0.0f;
        }
        __threadfence();                             // release spike stores
        if (lane == 0) atomicAdd(counter, 1u);       // device-scope by default
    }

    // ---- barrier: all 100 blocks co-resident (<=256 CUs), spin on counter
    __syncthreads();
    if (tid == 0) {
        while (__hip_atomic_load(counter, __ATOMIC_ACQUIRE, __HIP_MEMORY_SCOPE_AGENT) < 40u)
            __builtin_amdgcn_s_sleep(2);
        __threadfence();                             // belt-and-braces acquire
    }
    __syncthreads();

    // ---- phase B: block = output column o; out[b][o] = spike[b]·W_mlp[o] + b_mlp[o]
    const int o = blk;
    const int wave = tid >> 6, lane = tid & 63;

    float acc[BB];
    #pragma unroll
    for (int b = 0; b < BB; ++b) acc[b] = 0.f;

    #pragma unroll
    for (int i = 0; i < 5; ++i) {
        int col = i * 2048 + tid * 4;                // 512 thr × f4 = 2048 floats/iter
        if (col < RR) {                              // last valid f4 at 9996
            float4 w = *(const float4*)(Wmlp + (size_t)o * RR + col);
            #pragma unroll
            for (int b = 0; b < BB; ++b) {
                float4 s = *(const float4*)(spike_out + b * RR + col);
                acc[b] += w.x * s.x + w.y * s.y + w.z * s.z + w.w * s.w;
            }
        }
    }

    __shared__ float red[8][BB];
    #pragma unroll
    for (int b = 0; b < BB; ++b) {
        float v = acc[b];
        #pragma unroll
        for (int off = 32; off >= 1; off >>= 1) v += __shfl_xor(v, off, 64);
        if (lane == 0) red[wave][b] = v;
    }
    __syncthreads();
    if (tid < BB) {
        float v = 0.f;
        #pragma unroll
        for (int w = 0; w < 8; ++w) v += red[w][tid];
        out[tid * 100 + o] = v + bmlp[o];
    }
}

extern "C" void kernel_launch(void* const* d_in, const int* in_sizes, int n_in,
                              void* d_out, int out_size, void* d_ws, size_t ws_size,
                              hipStream_t stream) {
    const float* in1  = (const float*)d_in[0];
    const float* in2  = (const float*)d_in[1];
    const float* in3  = (const float*)d_in[2];
    const float* in4  = (const float*)d_in[3];
    const float* in5  = (const float*)d_in[4];
    const float* Wfc  = (const float*)d_in[5];
    const float* bfc  = (const float*)d_in[6];
    // d_in[7] = W_fv : multiplied by zero spikes — never read (saves 400 MB)
    const float* bfv  = (const float*)d_in[8];
    const float* Wmlp = (const float*)d_in[9];
    const float* bmlp = (const float*)d_in[10];

    float* out   = (float*)d_out;          // 8*100 = 800 floats
    float* spike = out + 800;              // 8*10000 floats (r_sumspike)

    float*    mem2    = (float*)d_ws;      // 80000 floats, layout [q][b][nb]
    unsigned* counter = (unsigned*)((char*)d_ws + 80000 * sizeof(float));

    // DIAGNOSTIC: kA twice (idempotent). dur - 66.6 = marginal (L3-warm) kA cost.
    kA_gemm<<<2000, 256, 0, stream>>>(in1, in2, in3, in4, in5, Wfc, bfc, bfv,
                                      mem2, counter);
    kA_gemm<<<2000, 256, 0, stream>>>(in1, in2, in3, in4, in5, Wfc, bfc, bfv,
                                      mem2, counter);
    kB_spike_out<<<100, 512, 0, stream>>>(mem2, Wmlp, bmlp, spike, out, counter);
}

// Round 11
// 86.622 us; speedup vs baseline: 1.6891x; 1.1445x over previous
//
#include <hip/hip_runtime.h>

#define BB   8
#define NBL  2000
#define RR   10000
#define RT   16          // rows per kA block
#define KSEG 400         // K-cols per wave = one input segment

// ---------------- kernel A v4 (output-stationary): mem2[q][b][nb] = x·W_fc + biases
// 625 blocks × 320 thr (5 waves). Wave w handles input segment w (cols w*400..+400).
// Lane (ksub=lane&15, rgrp=lane>>4) owns 4 rows × 8 batches in registers; k packed
// 4-wide (b128). ONE 4-level shuffle reduce per segment; LDS combine across waves.
__global__ __launch_bounds__(320, 3) void kA_gemm(
    const float* __restrict__ in1, const float* __restrict__ in2,
    const float* __restrict__ in3, const float* __restrict__ in4,
    const float* __restrict__ in5,
    const float* __restrict__ Wfc, const float* __restrict__ bfc,
    const float* __restrict__ bfv, float* __restrict__ mem2,
    unsigned* __restrict__ counter)
{
    // re-arm the kernel-B barrier every call (stream order publishes it before kB)
    if (blockIdx.x == 0 && threadIdx.x == 0) *counter = 0u;

    const int tid  = threadIdx.x;
    const int wave = tid >> 6;            // 0..4 = input segment
    const int lane = tid & 63;
    const int ksub = lane & 15;           // k sub-slot within segment
    const int rgrp = lane >> 4;           // 0..3 row-group
    const int rbase = blockIdx.x * RT;    // rows [rbase, rbase+16)
    const int r0    = rbase + rgrp * 4;   // this lane's 4 rows

    const float* xp = (wave == 0) ? in1 : (wave == 1) ? in2 : (wave == 2) ? in3
                    : (wave == 3) ? in4 : in5;           // wave-uniform
    const float* wp = Wfc + (size_t)r0 * 2000 + wave * KSEG;

    float acc[4][BB];
    #pragma unroll
    for (int i = 0; i < 4; ++i)
        #pragma unroll
        for (int b = 0; b < BB; ++b) acc[i][b] = 0.f;

    // 6 full 64-col steps: koff = ksub*4 + j*64  (max 380+3 < 400, no guard)
    #pragma unroll
    for (int j = 0; j < 6; ++j) {
        const int koff = ksub * 4 + j * 64;
        float4 w[4];
        #pragma unroll
        for (int i = 0; i < 4; ++i)
            w[i] = *(const float4*)(wp + (size_t)i * 2000 + koff);
        #pragma unroll
        for (int b = 0; b < BB; ++b) {
            const float4 xv = *(const float4*)(xp + b * KSEG + koff);
            #pragma unroll
            for (int i = 0; i < 4; ++i)
                acc[i][b] += w[i].x * xv.x + w[i].y * xv.y + w[i].z * xv.z + w[i].w * xv.w;
        }
    }
    // tail step: cols 384..399 — only ksub<4 participate
    if (ksub < 4) {
        const int koff = 384 + ksub * 4;
        float4 w[4];
        #pragma unroll
        for (int i = 0; i < 4; ++i)
            w[i] = *(const float4*)(wp + (size_t)i * 2000 + koff);
        #pragma unroll
        for (int b = 0; b < BB; ++b) {
            const float4 xv = *(const float4*)(xp + b * KSEG + koff);
            #pragma unroll
            for (int i = 0; i < 4; ++i)
                acc[i][b] += w[i].x * xv.x + w[i].y * xv.y + w[i].z * xv.z + w[i].w * xv.w;
        }
    }

    // ONE reduce over the 16 ksub lanes (4 levels), per 32 register outputs
    #pragma unroll
    for (int i = 0; i < 4; ++i)
        #pragma unroll
        for (int b = 0; b < BB; ++b) {
            float v = acc[i][b];
            v += __shfl_xor(v, 1, 16);
            v += __shfl_xor(v, 2, 16);
            v += __shfl_xor(v, 4, 16);
            v += __shfl_xor(v, 8, 16);
            acc[i][b] = v;
        }

    // cross-wave combine: 20 writer lanes (ksub==0), disjoint slots
    __shared__ float part[5][4][4][BB];   // [wave][rgrp][i][b] = 2.5 KB
    if (ksub == 0) {
        #pragma unroll
        for (int i = 0; i < 4; ++i)
            #pragma unroll
            for (int b = 0; b < BB; ++b)
                part[wave][rgrp][i][b] = acc[i][b];
    }
    __syncthreads();

    if (wave == 0) {
        #pragma unroll
        for (int t = 0; t < 2; ++t) {
            const int o  = lane * 2 + t;              // 0..127 outputs
            const int ri = o >> 3, b = o & 7;         // row-in-block, batch
            const int r  = rbase + ri;
            const int g  = ri >> 2, i = ri & 3;
            const float v = part[0][g][i][b] + part[1][g][i][b] + part[2][g][i][b]
                          + part[3][g][i][b] + part[4][g][i][b];
            mem2[((r % 5) * BB + b) * NBL + (r / 5)] = v + bfc[r] + bfv[r] + 0.05f;
        }
    }
}

// ---------------- kernel B: fused {radix-select nps + spike} -> barrier -> MLP GEMV
// (byte-identical to the 66.6 µs R8 version — single-variable experiment)
__device__ __forceinline__ unsigned sortkey(float f) {
    unsigned u = __float_as_uint(f);
    return (u & 0x80000000u) ? ~u : (u | 0x80000000u);
}
__device__ __forceinline__ float unsortkey(unsigned u) {
    unsigned ub = (u & 0x80000000u) ? (u ^ 0x80000000u) : ~u;
    return __uint_as_float(ub);
}

__global__ __launch_bounds__(512) void kB_spike_out(
    const float* __restrict__ mem2, const float* __restrict__ Wmlp,
    const float* __restrict__ bmlp, float* __restrict__ spike_out,
    float* __restrict__ out, unsigned* __restrict__ counter)
{
    const int tid = threadIdx.x;
    const int blk = blockIdx.x;                      // 100 blocks

    // ---- phase A: blocks 0..39, wave 0 only — exact order stats + spike write
    if (blk < 40 && tid < 64) {
        const int b = blk / 5, k = blk - b * 5;
        const int lane = tid;
        const float* src = mem2 + (k * BB + b) * NBL;

        float    f[32];
        unsigned u[32];
        #pragma unroll
        for (int i = 0; i < 32; ++i) {
            int nb = i * 64 + lane;
            f[i] = (nb < NBL) ? src[nb] : 0.f;
            u[i] = (nb < NBL) ? sortkey(f[i]) : 0u;  // pad key = smallest
        }

        // rank-159 (160th largest): max X with count(u >= X) >= 160 (ballot+popc)
        unsigned X = 0;
        for (int bit = 31; bit >= 0; --bit) {
            unsigned cand = X | (1u << bit);
            int c = 0;
            #pragma unroll
            for (int i = 0; i < 32; ++i)
                c += (int)__popcll(__ballot(u[i] >= cand));
            if (c >= 160) X = cand;
        }
        const unsigned q2u = X;                      // mem_q2 (rank 159)

        int cge = 0;
        #pragma unroll
        for (int i = 0; i < 32; ++i)
            cge += (int)__popcll(__ballot(u[i] >= q2u));

        unsigned q1u;
        if (cge >= 161) {
            q1u = q2u;                               // ties reach rank 160
        } else {
            unsigned m = 0;
            #pragma unroll
            for (int i = 0; i < 32; ++i)
                if (u[i] < q2u && u[i] > m) m = u[i];
            #pragma unroll
            for (int o = 32; o >= 1; o >>= 1) {
                unsigned ot = __shfl_xor(m, o, 64);
                m = (ot > m) ? ot : m;
            }
            q1u = m;                                 // mem_q1 (rank 160)
        }

        const float q2 = unsortkey(q2u), q1 = unsortkey(q1u);
        const float nps = q1 + (q2 - q1) * 0.2f;

        #pragma unroll
        for (int i = 0; i < 32; ++i) {
            int nb = i * 64 + lane;
            if (nb < NBL)
                spike_out[b * RR + nb * 5 + k] = (f[i] - nps > 0.1f) ? 1.0f : 0.0f;
        }
        __threadfence();                             // release spike stores
        if (lane == 0) atomicAdd(counter, 1u);       // device-scope by default
    }

    // ---- barrier: all 100 blocks co-resident (<=256 CUs), spin on counter
    __syncthreads();
    if (tid == 0) {
        while (__hip_atomic_load(counter, __ATOMIC_ACQUIRE, __HIP_MEMORY_SCOPE_AGENT) < 40u)
            __builtin_amdgcn_s_sleep(2);
        __threadfence();                             // belt-and-braces acquire
    }
    __syncthreads();

    // ---- phase B: block = output column o; out[b][o] = spike[b]·W_mlp[o] + b_mlp[o]
    const int o = blk;
    const int wave = tid >> 6, lane = tid & 63;

    float acc[BB];
    #pragma unroll
    for (int b = 0; b < BB; ++b) acc[b] = 0.f;

    #pragma unroll
    for (int i = 0; i < 5; ++i) {
        int col = i * 2048 + tid * 4;                // 512 thr × f4 = 2048 floats/iter
        if (col < RR) {                              // last valid f4 at 9996
            float4 w = *(const float4*)(Wmlp + (size_t)o * RR + col);
            #pragma unroll
            for (int b = 0; b < BB; ++b) {
                float4 s = *(const float4*)(spike_out + b * RR + col);
                acc[b] += w.x * s.x + w.y * s.y + w.z * s.z + w.w * s.w;
            }
        }
    }

    __shared__ float red[8][BB];
    #pragma unroll
    for (int b = 0; b < BB; ++b) {
        float v = acc[b];
        #pragma unroll
        for (int off = 32; off >= 1; off >>= 1) v += __shfl_xor(v, off, 64);
        if (lane == 0) red[wave][b] = v;
    }
    __syncthreads();
    if (tid < BB) {
        float v = 0.f;
        #pragma unroll
        for (int w = 0; w < 8; ++w) v += red[w][tid];
        out[tid * 100 + o] = v + bmlp[o];
    }
}

extern "C" void kernel_launch(void* const* d_in, const int* in_sizes, int n_in,
                              void* d_out, int out_size, void* d_ws, size_t ws_size,
                              hipStream_t stream) {
    const float* in1  = (const float*)d_in[0];
    const float* in2  = (const float*)d_in[1];
    const float* in3  = (const float*)d_in[2];
    const float* in4  = (const float*)d_in[3];
    const float* in5  = (const float*)d_in[4];
    const float* Wfc  = (const float*)d_in[5];
    const float* bfc  = (const float*)d_in[6];
    // d_in[7] = W_fv : multiplied by zero spikes — never read (saves 400 MB)
    const float* bfv  = (const float*)d_in[8];
    const float* Wmlp = (const float*)d_in[9];
    const float* bmlp = (const float*)d_in[10];

    float* out   = (float*)d_out;          // 8*100 = 800 floats
    float* spike = out + 800;              // 8*10000 floats (r_sumspike)

    float*    mem2    = (float*)d_ws;      // 80000 floats, layout [q][b][nb]
    unsigned* counter = (unsigned*)((char*)d_ws + 80000 * sizeof(float));

    kA_gemm<<<625, 320, 0, stream>>>(in1, in2, in3, in4, in5, Wfc, bfc, bfv,
                                     mem2, counter);
    kB_spike_out<<<100, 512, 0, stream>>>(mem2, Wmlp, bmlp, spike, out, counter);
}

// Round 12
// 71.189 us; speedup vs baseline: 2.0552x; 1.2168x over previous
//
#include <hip/hip_runtime.h>

#define BB   8
#define NBL  2000
#define RR   10000
#define XDIM 2000
#define GEMB 200        // kB blocks: (o = blk>>1, half = blk&1)
#define HALF 5000       // floats per GEMV half-chunk

// ---------------- kernel A (split-K×4, R8 champion): mem2[q][b][nb] = x·W_fc + biases
// 2000 blocks × 256 thr. Block owns ONE nb; 4 waves cover 512-col quarters.
// Block 0 additionally re-arms the kB counter and pre-initializes out = bias.
__global__ __launch_bounds__(256) void kA_gemm(
    const float* __restrict__ in1, const float* __restrict__ in2,
    const float* __restrict__ in3, const float* __restrict__ in4,
    const float* __restrict__ in5,
    const float* __restrict__ Wfc, const float* __restrict__ bfc,
    const float* __restrict__ bfv, const float* __restrict__ bmlp,
    float* __restrict__ mem2, float* __restrict__ out,
    unsigned* __restrict__ counter)
{
    const int tid  = threadIdx.x;
    if (blockIdx.x == 0) {
        if (tid == 0) *counter = 0u;
        for (int t = tid; t < 800; t += 256) out[t] = bmlp[t % 100];  // bias init
    }

    const int wave = tid >> 6, lane = tid & 63;     // wave = column quarter 0..3
    const int nb    = blockIdx.x;                   // 0..1999
    const int rbase = nb * 5;

    float acc[5][BB];
    #pragma unroll
    for (int q = 0; q < 5; ++q)
        #pragma unroll
        for (int b = 0; b < BB; ++b) acc[q][b] = 0.f;

    #pragma unroll
    for (int i = 0; i < 2; ++i) {
        const int col = wave * 512 + i * 256 + (lane << 2);   // float4-aligned
        const bool valid = col < XDIM;              // tail: wave==3,i==1, lanes>=52
        const int wh  = col / 400;                  // concat segment (5 only if invalid)
        const int off = col - wh * 400;             // f4 never crosses a 400-boundary
        const float* xp = in1;
        xp = (wh == 1) ? in2 : xp;
        xp = (wh == 2) ? in3 : xp;
        xp = (wh == 3) ? in4 : xp;
        xp = (wh == 4) ? in5 : xp;

        float4 w[5];
        #pragma unroll
        for (int q = 0; q < 5; ++q)
            w[q] = valid ? *(const float4*)(Wfc + (size_t)(rbase + q) * XDIM + col)
                         : make_float4(0.f, 0.f, 0.f, 0.f);

        #pragma unroll
        for (int b = 0; b < BB; ++b) {
            float4 xv = valid ? *(const float4*)(xp + b * 400 + off)
                              : make_float4(0.f, 0.f, 0.f, 0.f);
            #pragma unroll
            for (int q = 0; q < 5; ++q)
                acc[q][b] += w[q].x * xv.x + w[q].y * xv.y + w[q].z * xv.z + w[q].w * xv.w;
        }
    }

    // intra-wave reduce -> LDS partials -> wave 0 finalizes
    __shared__ float part[4][5][BB];                // [wave][q][b], 640 B
    #pragma unroll
    for (int q = 0; q < 5; ++q) {
        #pragma unroll
        for (int b = 0; b < BB; ++b) {
            float v = acc[q][b];
            #pragma unroll
            for (int o = 32; o >= 1; o >>= 1) v += __shfl_xor(v, o, 64);
            if (lane == 0) part[wave][q][b] = v;
        }
    }
    __syncthreads();

    if (wave == 0 && lane < 40) {                   // 40 outputs: q = lane>>3, b = lane&7
        const int q = lane >> 3, b = lane & 7;
        const int r = rbase + q;
        const float v = part[0][q][b] + part[1][q][b] + part[2][q][b] + part[3][q][b];
        mem2[(q * BB + b) * NBL + nb] = v + bfc[r] + bfv[r] + 0.05f;
    }
}

// ---------------- kernel B: select+spike (40 waves) -> barrier -> split-K GEMV
__device__ __forceinline__ unsigned sortkey(float f) {
    unsigned u = __float_as_uint(f);
    return (u & 0x80000000u) ? ~u : (u | 0x80000000u);
}
__device__ __forceinline__ float unsortkey(unsigned u) {
    unsigned ub = (u & 0x80000000u) ? (u ^ 0x80000000u) : ~u;
    return __uint_as_float(ub);
}

__global__ __launch_bounds__(256) void kB_spike_out(
    const float* __restrict__ mem2, const float* __restrict__ Wmlp,
    float* __restrict__ spike_out, float* __restrict__ out,
    unsigned* __restrict__ counter)
{
    const int tid = threadIdx.x;
    const int blk = blockIdx.x;                      // 200 blocks
    const int o   = blk >> 1;                        // output column 0..99
    const int h   = blk & 1;                         // column half 0/1

    // ---- prefetch this block's W_mlp slice into registers (hides under barrier wait)
    float4 wv[5];
    #pragma unroll
    for (int i = 0; i < 5; ++i) {
        const int col = i * 1024 + tid * 4;          // 0..5116
        wv[i] = (col < HALF) ? *(const float4*)(Wmlp + (size_t)o * RR + h * HALF + col)
                             : make_float4(0.f, 0.f, 0.f, 0.f);
    }

    // ---- phase A: blocks 0..39, wave 0 only — exact order stats + spike write
    if (blk < 40 && tid < 64) {
        const int b = blk / 5, k = blk - b * 5;
        const int lane = tid;
        const float* src = mem2 + (k * BB + b) * NBL;

        float    f[32];
        unsigned u[32];
        #pragma unroll
        for (int i = 0; i < 32; ++i) {
            int nb = i * 64 + lane;
            f[i] = (nb < NBL) ? src[nb] : 0.f;
            u[i] = (nb < NBL) ? sortkey(f[i]) : 0u;  // pad key = smallest
        }

        // rank-159 (160th largest): max X with count(u >= X) >= 160 (ballot+popc)
        unsigned X = 0;
        for (int bit = 31; bit >= 0; --bit) {
            unsigned cand = X | (1u << bit);
            int c = 0;
            #pragma unroll
            for (int i = 0; i < 32; ++i)
                c += (int)__popcll(__ballot(u[i] >= cand));
            if (c >= 160) X = cand;
        }
        const unsigned q2u = X;                      // mem_q2 (rank 159)

        int cge = 0;
        #pragma unroll
        for (int i = 0; i < 32; ++i)
            cge += (int)__popcll(__ballot(u[i] >= q2u));

        unsigned q1u;
        if (cge >= 161) {
            q1u = q2u;                               // ties reach rank 160
        } else {
            unsigned m = 0;
            #pragma unroll
            for (int i = 0; i < 32; ++i)
                if (u[i] < q2u && u[i] > m) m = u[i];
            #pragma unroll
            for (int oo = 32; oo >= 1; oo >>= 1) {
                unsigned ot = __shfl_xor(m, oo, 64);
                m = (ot > m) ? ot : m;
            }
            q1u = m;                                 // mem_q1 (rank 160)
        }

        const float q2 = unsortkey(q2u), q1 = unsortkey(q1u);
        const float nps = q1 + (q2 - q1) * 0.2f;

        #pragma unroll
        for (int i = 0; i < 32; ++i) {
            int nb = i * 64 + lane;
            if (nb < NBL)
                spike_out[b * RR + nb * 5 + k] = (f[i] - nps > 0.1f) ? 1.0f : 0.0f;
        }
        __threadfence();                             // release spike stores
        if (lane == 0) atomicAdd(counter, 1u);       // device-scope by default
    }

    // ---- barrier: all 200 blocks co-resident, spin (low-rate poll) on counter
    __syncthreads();
    if (tid == 0) {
        while (__hip_atomic_load(counter, __ATOMIC_ACQUIRE, __HIP_MEMORY_SCOPE_AGENT) < 40u)
            __builtin_amdgcn_s_sleep(4);
        __threadfence();                             // acquire
    }
    __syncthreads();

    // ---- phase B: partial GEMV  out[b][o] += spike[b][half]·W_mlp[o][half]
    const int wave = tid >> 6, lane = tid & 63;

    float acc[BB];
    #pragma unroll
    for (int b = 0; b < BB; ++b) acc[b] = 0.f;

    #pragma unroll
    for (int i = 0; i < 5; ++i) {
        const int col = i * 1024 + tid * 4;
        if (col < HALF) {
            #pragma unroll
            for (int b = 0; b < BB; ++b) {
                float4 s = *(const float4*)(spike_out + b * RR + h * HALF + col);
                acc[b] += wv[i].x * s.x + wv[i].y * s.y + wv[i].z * s.z + wv[i].w * s.w;
            }
        }
    }

    __shared__ float red[4][BB];
    #pragma unroll
    for (int b = 0; b < BB; ++b) {
        float v = acc[b];
        #pragma unroll
        for (int off = 32; off >= 1; off >>= 1) v += __shfl_xor(v, off, 64);
        if (lane == 0) red[wave][b] = v;
    }
    __syncthreads();
    if (tid < BB) {
        const float v = red[0][tid] + red[1][tid] + red[2][tid] + red[3][tid];
        atomicAdd(&out[tid * 100 + o], v);           // 2 adds/address, commut.-exact
    }
}

extern "C" void kernel_launch(void* const* d_in, const int* in_sizes, int n_in,
                              void* d_out, int out_size, void* d_ws, size_t ws_size,
                              hipStream_t stream) {
    const float* in1  = (const float*)d_in[0];
    const float* in2  = (const float*)d_in[1];
    const float* in3  = (const float*)d_in[2];
    const float* in4  = (const float*)d_in[3];
    const float* in5  = (const float*)d_in[4];
    const float* Wfc  = (const float*)d_in[5];
    const float* bfc  = (const float*)d_in[6];
    // d_in[7] = W_fv : multiplied by zero spikes — never read (saves 400 MB)
    const float* bfv  = (const float*)d_in[8];
    const float* Wmlp = (const float*)d_in[9];
    const float* bmlp = (const float*)d_in[10];

    float* out   = (float*)d_out;          // 8*100 = 800 floats
    float* spike = out + 800;              // 8*10000 floats (r_sumspike)

    float*    mem2    = (float*)d_ws;      // 80000 floats, layout [q][b][nb]
    unsigned* counter = (unsigned*)((char*)d_ws + 80000 * sizeof(float));

    kA_gemm<<<2000, 256, 0, stream>>>(in1, in2, in3, in4, in5, Wfc, bfc, bfv,
                                      bmlp, mem2, out, counter);
    kB_spike_out<<<GEMB, 256, 0, stream>>>(mem2, Wmlp, spike, out, counter);
}